// Round 1
// baseline (336.883 us; speedup 1.0000x reference)
//
#include <hip/hip_runtime.h>
#include <math.h>

// HighDimAELoss: associative-embedding push/pull loss.
// tags [B,D,R,R] fp32; joints [B,M,J,2] int32 (flat idx, visibility).
// out: push[B] ++ pull[B] (fp32).
// One block per image; gather t[m][j][d] into LDS, reduce in shared mem.

constexpr int B_ = 16, M_ = 30, J_ = 17, D_ = 17, R_ = 512;

__global__ __launch_bounds__(512) void ae_loss_kernel(
    const float* __restrict__ tags, const int* __restrict__ joints,
    float* __restrict__ out) {
  const int b = blockIdx.x;
  const int tid = threadIdx.x;
  const int nthr = blockDim.x;

  __shared__ float t_s[M_][J_][D_];     // gathered tag vectors  (34.7 KB)
  __shared__ float valid_s[M_][J_];
  __shared__ float cnt_s[M_];           // #valid joints per person
  __shared__ float pullnum_s[M_];       // sum_j sq*valid per person
  __shared__ float mean_s[M_][D_];      // per-person mean tag
  __shared__ float pv_s[M_];            // person_valid
  __shared__ float scal_s[2];           // n_tags, pull
  __shared__ float wavered[8];

  if (tid < M_) { cnt_s[tid] = 0.f; pullnum_s[tid] = 0.f; }
  __syncthreads();

  const float* tag_b = tags + (size_t)b * D_ * R_ * R_;
  const int* jb = joints + b * M_ * J_ * 2;

  // Phase 1: one thread per (m,j) — gather D values, compute sq via
  // sum_{d,e}(t_d-t_e)^2 = 2*(D*sum(t^2) - (sum t)^2)
  for (int mj = tid; mj < M_ * J_; mj += nthr) {
    const int m = mj / J_;
    const int j = mj - m * J_;
    int off = jb[2 * mj];
    const int vis = jb[2 * mj + 1];
    off %= (R_ * R_);
    if (off < 0) off += R_ * R_;
    const int x = off % R_;       // first spatial axis (torch convention)
    const int y = off / R_;
    const float* p = tag_b + x * R_ + y;
    float s1 = 0.f, s2 = 0.f;
#pragma unroll
    for (int d = 0; d < D_; ++d) {
      const float v = p[(size_t)d * (R_ * R_)];
      t_s[m][j][d] = v;
      s1 += v;
      s2 += v * v;
    }
    const float val = (vis > 0) ? 1.f : 0.f;
    valid_s[m][j] = val;
    const float sq = 2.f * ((float)D_ * s2 - s1 * s1);
    atomicAdd(&pullnum_s[m], sq * val);
    atomicAdd(&cnt_s[m], val);
  }
  __syncthreads();

  // Phase 2: mean_tag per (m,d)
  for (int i = tid; i < M_ * D_; i += nthr) {
    const int m = i / D_;
    const int d = i - m * D_;
    float s = 0.f;
#pragma unroll
    for (int j = 0; j < J_; ++j) s += t_s[m][j][d] * valid_s[m][j];
    mean_s[m][d] = s / fmaxf(cnt_s[m], 1.f);
  }
  if (tid < M_) pv_s[tid] = (cnt_s[tid] > 0.f) ? 1.f : 0.f;
  __syncthreads();

  // Phase 3: n_tags + pull (serial over 30 — negligible)
  if (tid == 0) {
    float nt = 0.f, pull = 0.f;
    for (int m = 0; m < M_; ++m) {
      nt += pv_s[m];
      const float safe = fmaxf(cnt_s[m], 1.f);
      pull += pv_s[m] * pullnum_s[m] / ((float)(D_ * D_) * safe);
    }
    scal_s[0] = nt;
    scal_s[1] = pull / fmaxf(nt, 1.f);
  }
  __syncthreads();

  // Phase 4: push over M*M person pairs (diagonal included, as in ref)
  float acc = 0.f;
  for (int mn = tid; mn < M_ * M_; mn += nthr) {
    const int m = mn / M_;
    const int n = mn - m * M_;
    const float w = pv_s[m] * pv_s[n];
    if (w > 0.f) {
      float s = 0.f;
#pragma unroll
      for (int d = 0; d < D_; ++d) {
        const float pd = mean_s[m][d] - mean_s[n][d];
        s += expf(-pd * pd);
      }
      acc += s * (1.f / (float)D_) * w;
    }
  }
  // block reduction: wave64 shuffle then cross-wave via LDS
#pragma unroll
  for (int o = 32; o > 0; o >>= 1) acc += __shfl_down(acc, o, 64);
  const int wave = tid >> 6;
  const int lane = tid & 63;
  if (lane == 0) wavered[wave] = acc;
  __syncthreads();
  if (tid == 0) {
    float tot = 0.f;
    for (int w = 0; w < (nthr >> 6); ++w) tot += wavered[w];
    const float nt = scal_s[0];
    const float safe_nt = fmaxf(nt, 1.f);
    const float push = (nt >= 2.f) ? tot / (safe_nt * safe_nt) : 0.f;
    out[b] = push;        // push[b]
    out[B_ + b] = scal_s[1];  // pull[b]
  }
}

extern "C" void kernel_launch(void* const* d_in, const int* in_sizes, int n_in,
                              void* d_out, int out_size, void* d_ws, size_t ws_size,
                              hipStream_t stream) {
  const float* tags = (const float*)d_in[0];
  const int* joints = (const int*)d_in[1];
  float* out = (float*)d_out;
  ae_loss_kernel<<<B_, 512, 0, stream>>>(tags, joints, out);
}

// Round 2
// 319.958 us; speedup vs baseline: 1.0529x; 1.0529x over previous
//
#include <hip/hip_runtime.h>
#include <math.h>

// HighDimAELoss: associative-embedding push/pull loss.
// tags [B,D,R,R] fp32; joints [B,M,J,2] int32 (flat idx, visibility).
// out: push[B] ++ pull[B] (fp32).
//
// Two-kernel structure:
//  K1: one thread per (b,m,j,d) scattered gather -> ws (uses all 256 CUs for
//      max memory-level parallelism; the single-kernel version pinned the
//      8670 scattered misses per image onto one CU each = latency-serialized).
//  K2: one block per image; all reductions from the L2-resident ws copy.

constexpr int B_ = 16, M_ = 30, J_ = 17, D_ = 17, R_ = 512;
constexpr int TOT_ = B_ * M_ * J_ * D_;   // 138720 gathered elements

__global__ __launch_bounds__(256) void ae_gather_kernel(
    const float* __restrict__ tags, const int* __restrict__ joints,
    float* __restrict__ t_ws) {
  const int i = blockIdx.x * blockDim.x + threadIdx.x;
  if (i >= TOT_) return;
  const int d = i % D_;
  const int bmj = i / D_;                 // b*M*J + m*J + j
  const int b = bmj / (M_ * J_);
  int off = joints[2 * bmj];
  off %= (R_ * R_);
  if (off < 0) off += R_ * R_;
  const int x = off % R_;                 // first spatial axis (torch convention)
  const int y = off / R_;
  t_ws[i] = tags[(((size_t)b * D_ + d) * R_ + x) * R_ + y];
}

__global__ __launch_bounds__(512) void ae_reduce_kernel(
    const float* __restrict__ t_ws, const int* __restrict__ joints,
    float* __restrict__ out) {
  const int b = blockIdx.x;
  const int tid = threadIdx.x;
  const int nthr = blockDim.x;

  __shared__ float t_s[M_][J_][D_];     // gathered tag vectors  (34.7 KB)
  __shared__ float valid_s[M_][J_];
  __shared__ float cnt_s[M_];           // #valid joints per person
  __shared__ float pullnum_s[M_];       // sum_j sq*valid per person
  __shared__ float mean_s[M_][D_];      // per-person mean tag
  __shared__ float pv_s[M_];            // person_valid
  __shared__ float scal_s[2];           // n_tags, pull
  __shared__ float wavered[8];

  if (tid < M_) { cnt_s[tid] = 0.f; pullnum_s[tid] = 0.f; }
  __syncthreads();

  const int* jb = joints + b * M_ * J_ * 2;
  const float* tb = t_ws + (size_t)b * M_ * J_ * D_;

  // Phase 1: one thread per (m,j) — read D contiguous values from ws (L2 hit),
  // sq via sum_{d,e}(t_d-t_e)^2 = 2*(D*sum(t^2) - (sum t)^2)
  for (int mj = tid; mj < M_ * J_; mj += nthr) {
    const int m = mj / J_;
    const int j = mj - m * J_;
    const int vis = jb[2 * mj + 1];
    const float* p = tb + (size_t)mj * D_;
    float s1 = 0.f, s2 = 0.f;
#pragma unroll
    for (int d = 0; d < D_; ++d) {
      const float v = p[d];
      t_s[m][j][d] = v;
      s1 += v;
      s2 += v * v;
    }
    const float val = (vis > 0) ? 1.f : 0.f;
    valid_s[m][j] = val;
    const float sq = 2.f * ((float)D_ * s2 - s1 * s1);
    atomicAdd(&pullnum_s[m], sq * val);
    atomicAdd(&cnt_s[m], val);
  }
  __syncthreads();

  // Phase 2: mean_tag per (m,d)
  for (int i = tid; i < M_ * D_; i += nthr) {
    const int m = i / D_;
    const int d = i - m * D_;
    float s = 0.f;
#pragma unroll
    for (int j = 0; j < J_; ++j) s += t_s[m][j][d] * valid_s[m][j];
    mean_s[m][d] = s / fmaxf(cnt_s[m], 1.f);
  }
  if (tid < M_) pv_s[tid] = (cnt_s[tid] > 0.f) ? 1.f : 0.f;
  __syncthreads();

  // Phase 3: n_tags + pull (serial over 30 — negligible)
  if (tid == 0) {
    float nt = 0.f, pull = 0.f;
    for (int m = 0; m < M_; ++m) {
      nt += pv_s[m];
      const float safe = fmaxf(cnt_s[m], 1.f);
      pull += pv_s[m] * pullnum_s[m] / ((float)(D_ * D_) * safe);
    }
    scal_s[0] = nt;
    scal_s[1] = pull / fmaxf(nt, 1.f);
  }
  __syncthreads();

  // Phase 4: push over M*M person pairs (diagonal included, as in ref)
  float acc = 0.f;
  for (int mn = tid; mn < M_ * M_; mn += nthr) {
    const int m = mn / M_;
    const int n = mn - m * M_;
    const float w = pv_s[m] * pv_s[n];
    if (w > 0.f) {
      float s = 0.f;
#pragma unroll
      for (int d = 0; d < D_; ++d) {
        const float pd = mean_s[m][d] - mean_s[n][d];
        s += expf(-pd * pd);
      }
      acc += s * (1.f / (float)D_) * w;
    }
  }
  // block reduction: wave64 shuffle then cross-wave via LDS
#pragma unroll
  for (int o = 32; o > 0; o >>= 1) acc += __shfl_down(acc, o, 64);
  const int wave = tid >> 6;
  const int lane = tid & 63;
  if (lane == 0) wavered[wave] = acc;
  __syncthreads();
  if (tid == 0) {
    float tot = 0.f;
    for (int w = 0; w < (nthr >> 6); ++w) tot += wavered[w];
    const float nt = scal_s[0];
    const float safe_nt = fmaxf(nt, 1.f);
    const float push = (nt >= 2.f) ? tot / (safe_nt * safe_nt) : 0.f;
    out[b] = push;            // push[b]
    out[B_ + b] = scal_s[1];  // pull[b]
  }
}

extern "C" void kernel_launch(void* const* d_in, const int* in_sizes, int n_in,
                              void* d_out, int out_size, void* d_ws, size_t ws_size,
                              hipStream_t stream) {
  const float* tags = (const float*)d_in[0];
  const int* joints = (const int*)d_in[1];
  float* out = (float*)d_out;
  float* t_ws = (float*)d_ws;   // B*M*J*D floats = 555 KB

  ae_gather_kernel<<<(TOT_ + 255) / 256, 256, 0, stream>>>(tags, joints, t_ws);
  ae_reduce_kernel<<<B_, 512, 0, stream>>>(t_ws, joints, out);
}